// Round 6
// baseline (37.968 us; speedup 1.0000x reference)
//
#include <hip/hip_runtime.h>

// GuidedMoEBasic single-launch, fence-free producer->consumer handoff.
// B=16, D=64, H=768, NE=7, FEAT=776. Affine collapse of the expert MLP:
//   o[e,n,:] = flat[n]@(W1[e]@W2[e]) + (b1[e]@W2[e]+b2[e]),
//   flat[n] = [conc[b,t], conc[b,end]] -> per-row 12-float pc vectors,
//   pairs O(1) from pc. Bt[12][800] f32 in ws = 8 M-columns + 4 gate columns.
// Producers (194 M blocks + 1 misc) write Bt/bc with RELAXED AGENT atomic
// stores (coherent at IF$, no L2 writeback), __syncthreads (drains vmcnt)
// then one relaxed atomicAdd arrive. 16 consumer blocks overlap A-preload +
// emotion self-compute with producers, poll the counter (bounded), stage Bt
// to LDS via agent atomic loads, MFMA-project, O(1) pairs. No threadfence,
// no release fences anywhere. Counters are __device__ globals reset by the
// last departing consumer (replay-safe, immune to ws/out poison).

#define NE_    7
#define H_     768
#define FEAT_  776
#define NROW   1024
#define PAIRS  2080
#define KP     800          // padded K (25 * 32)
#define BTJ    12
#define NBATCH 16
#define NMBLK  194          // 194 * 16 waves = 3104 M-rows
#define MISCB  194
#define NPROD  195
#define CONS0  195
#define NBLKS  211

__device__ int g_arr = 0;
__device__ int g_dep = 0;

typedef float f32x4 __attribute__((ext_vector_type(4)));
typedef short bf16x8 __attribute__((ext_vector_type(8)));

__device__ __forceinline__ unsigned short f2b(float x) {
    unsigned u = __float_as_uint(x);
    u += 0x7FFFu + ((u >> 16) & 1u);
    return (unsigned short)(u >> 16);
}

__device__ __forceinline__ void st_agent(float* p, float v) {
    __hip_atomic_store(p, v, __ATOMIC_RELAXED, __HIP_MEMORY_SCOPE_AGENT);
}

__global__ __launch_bounds__(1024) void kOne(
        const float* __restrict__ pooled,
        const int*   __restrict__ spk,
        const float* __restrict__ emo_w,
        const float* __restrict__ emo_b,
        const float* __restrict__ gate_w,
        const float* __restrict__ gate_b,
        const float* __restrict__ w1,
        const float* __restrict__ b1,
        const float* __restrict__ w2,
        const float* __restrict__ b2,
        float* __restrict__ out,                // [1024*7] emo | [33280*2] cause
        float* __restrict__ wsBt,               // [12][800] f32
        float* __restrict__ wsbc) {             // [4] f32
    const int blk = blockIdx.x;
    const int tid = threadIdx.x;
    const int l   = tid & 63;
    const int wv  = tid >> 6;

    // ================= M producer blocks: one M-row per wave =================
    if (blk < NMBLK) {
        const int mr = blk * 16 + wv;                     // 0..3103
        const int e = mr / 1552, rr = mr - e * 1552;
        const float4 a = ((const float4*)(w1 + ((size_t)e * 1552 + rr) * 256))[l];
        const float4* wvp = (const float4*)(w2 + (size_t)e * 512);
        const float4 q0 = wvp[l * 2], q1 = wvp[l * 2 + 1];
        float a0 = a.x * q0.x + a.y * q0.z + a.z * q1.x + a.w * q1.z;
        float a1 = a.x * q0.y + a.y * q0.w + a.z * q1.y + a.w * q1.w;
#pragma unroll
        for (int off = 32; off; off >>= 1) {
            a0 += __shfl_down(a0, off);
            a1 += __shfl_down(a1, off);
        }
        if (l == 0) {
            const int half = rr / FEAT_, f = rr - half * FEAT_;
            const int j = half * 4 + e * 2;
            st_agent(wsBt + j * KP + f, a0);
            st_agent(wsBt + (j + 1) * KP + f, a1);
        }
        __syncthreads();                                  // drains vmcnt per wave
        if (tid == 0) atomicAdd(&g_arr, 1);
        return;
    }

    // ================= misc producer: bc, gate columns, pads =================
    if (blk == MISCB) {
        if (wv < 2) {
            const int e = wv;
            const float4 a = ((const float4*)(b1 + e * 256))[l];
            const float4* wvp = (const float4*)(w2 + (size_t)e * 512);
            const float4 q0 = wvp[l * 2], q1 = wvp[l * 2 + 1];
            float a0 = a.x * q0.x + a.y * q0.z + a.z * q1.x + a.w * q1.z;
            float a1 = a.x * q0.y + a.y * q0.w + a.z * q1.y + a.w * q1.w;
#pragma unroll
            for (int off = 32; off; off >>= 1) {
                a0 += __shfl_down(a0, off);
                a1 += __shfl_down(a1, off);
            }
            if (l == 0) {
                st_agent(wsbc + e * 2,     a0 + b2[e * 2]);
                st_agent(wsbc + e * 2 + 1, a1 + b2[e * 2 + 1]);
            }
        }
        for (int gi = tid; gi < 3104; gi += 1024) {
            const int half = gi / 1552, r2 = gi - half * 1552, f = r2 >> 1, c = r2 & 1;
            st_agent(wsBt + (8 + half * 2 + c) * KP + f,
                     gate_w[((size_t)half * FEAT_ + f) * 2 + c]);
        }
        for (int z = tid; z < BTJ * 24; z += 1024) {
            const int j = z / 24, f = FEAT_ + z % 24;
            st_agent(wsBt + j * KP + f, 0.0f);
        }
        __syncthreads();
        if (tid == 0) atomicAdd(&g_arr, 1);
        return;
    }

    // ================= consumer blocks (one per batch) =================
    const int b = blk - CONS0, R0 = b * 64;
    __shared__ __align__(16) short sBt[BTJ * KP];         // 19,200 B
    __shared__ float emoL[64][8];                         //  2,048 B
    __shared__ float part[4096];                          // 16,384 B

    const int m = wv & 3, kq = wv >> 2, g = l >> 4, n = l & 15;
    const int arow = R0 + m * 16 + n;
    const int kt0 = (kq == 0) ? 0 : (1 + 6 * kq);         // k-steps 7,6,6,6
    const int cnt = (kq == 0) ? 7 : 6;

    // --- producer-independent work 1: A-fragment preload from pooled ---
    bf16x8 af[7];
#pragma unroll
    for (int s = 0; s < 7; ++s) {
        bf16x8 t = {0, 0, 0, 0, 0, 0, 0, 0};
        if (s < cnt) {
            const int k0 = (kt0 + s) * 32 + g * 8;
            if (k0 < H_) {
                const float4 u0 = *(const float4*)(pooled + (size_t)arow * H_ + k0);
                const float4 u1 = *(const float4*)(pooled + (size_t)arow * H_ + k0 + 4);
                t[0] = (short)f2b(u0.x); t[1] = (short)f2b(u0.y);
                t[2] = (short)f2b(u0.z); t[3] = (short)f2b(u0.w);
                t[4] = (short)f2b(u1.x); t[5] = (short)f2b(u1.y);
                t[6] = (short)f2b(u1.z); t[7] = (short)f2b(u1.w);
            }
        }
        af[s] = t;
    }

    // --- producer-independent work 2: emotion rows (wave wv -> 4 rows) ---
#pragma unroll
    for (int r4 = 0; r4 < 4; ++r4) {
        const int lr = wv * 4 + r4;
        const float* pr = pooled + (size_t)(R0 + lr) * H_;
        float acc[NE_] = {0.f, 0.f, 0.f, 0.f, 0.f, 0.f, 0.f};
#pragma unroll
        for (int i = 0; i < 12; ++i) {
            const float p = pr[l + 64 * i];
            const float* ew = emo_w + (size_t)(l + 64 * i) * NE_;
#pragma unroll
            for (int k = 0; k < NE_; ++k) acc[k] += p * ew[k];
        }
#pragma unroll
        for (int off = 32; off; off >>= 1)
#pragma unroll
            for (int k = 0; k < NE_; ++k) acc[k] += __shfl_down(acc[k], off);
        if (l == 0) {
#pragma unroll
            for (int k = 0; k < NE_; ++k) {
                const float v = acc[k] + emo_b[k];
                out[(size_t)(R0 + lr) * NE_ + k] = v;
                emoL[lr][k] = v;
            }
            emoL[lr][7] = (float)spk[R0 + lr];
        }
    }
    __syncthreads();

    // emotion/spk A-fragment fixup (k 768..775): kq==3, s=5 -> kt=24, g==0
    if (kq == 3 && g == 0) {
        const int lr = m * 16 + n;
        bf16x8 t;
        t[0] = (short)f2b(emoL[lr][0]); t[1] = (short)f2b(emoL[lr][1]);
        t[2] = (short)f2b(emoL[lr][2]); t[3] = (short)f2b(emoL[lr][3]);
        t[4] = (short)f2b(emoL[lr][4]); t[5] = (short)f2b(emoL[lr][5]);
        t[6] = (short)f2b(emoL[lr][6]); t[7] = (short)f2b(emoL[lr][7]);
        af[5] = t;
    }

    // --- handoff: bounded poll on arrive counter (no fences) ---
    if (tid == 0) {
        int guard = 0;
        while (__hip_atomic_load(&g_arr, __ATOMIC_RELAXED, __HIP_MEMORY_SCOPE_AGENT) < NPROD
               && ++guard < (1 << 20))
            __builtin_amdgcn_s_sleep(2);
    }
    __syncthreads();
    if (tid == 0) {
        const int d = atomicAdd(&g_dep, 1);
        if (d == NBATCH - 1) {                            // last consumer resets
            __hip_atomic_store(&g_arr, 0, __ATOMIC_RELAXED, __HIP_MEMORY_SCOPE_AGENT);
            __hip_atomic_store(&g_dep, 0, __ATOMIC_RELAXED, __HIP_MEMORY_SCOPE_AGENT);
        }
    }

    // --- stage Bt -> LDS bf16 via agent atomic loads (coherent reads) ---
    for (int i = tid; i < BTJ * KP / 2; i += 1024) {
        const unsigned long long v = __hip_atomic_load(
            (const unsigned long long*)wsBt + i, __ATOMIC_RELAXED, __HIP_MEMORY_SCOPE_AGENT);
        sBt[i * 2]     = (short)f2b(__uint_as_float((unsigned)v));
        sBt[i * 2 + 1] = (short)f2b(__uint_as_float((unsigned)(v >> 32)));
    }
    __syncthreads();

    // --- MFMA: 25 k-steps over 4 k-quarters, 4 m-tiles, N=16 (12 used) ---
    f32x4 acc = {0.f, 0.f, 0.f, 0.f};
#pragma unroll
    for (int s = 0; s < 7; ++s) {
        if (s < cnt) {
            const int k0 = (kt0 + s) * 32 + g * 8;
            bf16x8 bfr = {0, 0, 0, 0, 0, 0, 0, 0};
            if (n < BTJ)
                bfr = *(const bf16x8*)(sBt + n * KP + k0);
            acc = __builtin_amdgcn_mfma_f32_16x16x32_bf16(af[s], bfr, acc, 0, 0, 0);
        }
    }
#pragma unroll
    for (int i = 0; i < 4; ++i)
        part[(kq * 64 + m * 16 + g * 4 + i) * 16 + n] = acc[i];
    __syncthreads();

    // cross-kq reduce into part[0]
    {
        const int r = tid >> 4, c = tid & 15;
        const float v = part[r * 16 + c] + part[(64 + r) * 16 + c] +
                        part[(128 + r) * 16 + c] + part[(192 + r) * 16 + c];
        part[r * 16 + c] = v;
    }
    __syncthreads();

    // --- pairs: O(1) each from part[0] (pc[64][16]) ---
    const unsigned long long c01 = __hip_atomic_load(
        (const unsigned long long*)wsbc, __ATOMIC_RELAXED, __HIP_MEMORY_SCOPE_AGENT);
    const unsigned long long c23 = __hip_atomic_load(
        (const unsigned long long*)wsbc + 1, __ATOMIC_RELAXED, __HIP_MEMORY_SCOPE_AGENT);
    const float bc0 = __uint_as_float((unsigned)c01);
    const float bc1 = __uint_as_float((unsigned)(c01 >> 32));
    const float bc2 = __uint_as_float((unsigned)c23);
    const float bc3 = __uint_as_float((unsigned)(c23 >> 32));
    const float gb0 = gate_b[0], gb1 = gate_b[1];
    float* oc = out + (size_t)NROW * NE_ + (size_t)b * PAIRS * 2;
    for (int p = tid; p < PAIRS; p += 1024) {
        int end = (int)((sqrtf(8.0f * (float)p + 1.0f) - 1.0f) * 0.5f);
        while ((end + 1) * (end + 2) / 2 <= p) end++;
        while (end * (end + 1) / 2 > p) end--;
        const int tt = p - end * (end + 1) / 2;
        const float* pt = part + tt * 16;
        const float* pe = part + end * 16;
        const float g0 = pt[8] + pe[10] + gb0;
        const float g1 = pt[9] + pe[11] + gb1;
        oc[p * 2]     = (pt[0] + pe[4] + bc0) * g0 + (pt[2] + pe[6] + bc2) * g1;
        oc[p * 2 + 1] = (pt[1] + pe[5] + bc1) * g0 + (pt[3] + pe[7] + bc3) * g1;
    }
}

// ---------------------------------------------------------------------------
extern "C" void kernel_launch(void* const* d_in, const int* in_sizes, int n_in,
                              void* d_out, int out_size, void* d_ws, size_t ws_size,
                              hipStream_t stream) {
    const float* pooled = (const float*)d_in[0];
    const int*   spk    = (const int*)d_in[1];
    const float* emo_w  = (const float*)d_in[2];
    const float* emo_b  = (const float*)d_in[3];
    const float* gate_w = (const float*)d_in[4];
    const float* gate_b = (const float*)d_in[5];
    const float* exp_w1 = (const float*)d_in[6];
    const float* exp_b1 = (const float*)d_in[7];
    const float* exp_w2 = (const float*)d_in[8];
    const float* exp_b2 = (const float*)d_in[9];

    float* out  = (float*)d_out;
    float* wsBt = (float*)d_ws;                          // 12*800*4 = 38,400 B
    float* wsbc = wsBt + BTJ * KP;                       // 16 B (8-aligned)

    hipLaunchKernelGGL(kOne, dim3(NBLKS), dim3(1024), 0, stream,
                       pooled, spk, emo_w, emo_b, gate_w, gate_b,
                       exp_w1, exp_b1, exp_w2, exp_b2, out, wsBt, wsbc);
}

// Round 7
// 37.701 us; speedup vs baseline: 1.0071x; 1.0071x over previous
//
#include <hip/hip_runtime.h>

// GuidedMoEBasic single-launch, RMW-free producer->consumer handoff.
// B=16, D=64, H=768, NE=7, FEAT=776. Affine collapse of the expert MLP:
//   o[e,n,:] = flat[n]@(W1[e]@W2[e]) + (b1[e]@W2[e]+b2[e]),
//   flat[n] = [conc[b,t], conc[b,end]] -> per-row 12-float pc vectors,
//   pairs O(1) from pc.
// Sync model (measured R2/R4/R6): same-address agent atomic RMWs serialize at
// ~200ns each -> NO atomicAdd anywhere. Producers signal via per-block flag
// STORES (distinct addresses, parallel); consumers poll with per-lane LOADS.
// Data goes through ws with relaxed agent (sc1) stores/loads - verified R6.
// Flags are __device__ globals reset by consumer block 0 after all consumers
// depart (replay-safe, immune to ws/out 0xAA poison).

#define NE_    7
#define H_     768
#define FEAT_  776
#define NROW   1024
#define PAIRS  2080
#define WKP    776          // wsBt row stride (f32, packed)
#define LKP    808          // LDS sBt row stride (bf16, 16B-aligned, conflict-spread)
#define NPROD  194          // 194 blocks * 16 waves = 3104 M-rows
#define NBATCH 16
#define CONS0  194
#define NBLKS  210

__device__ int g_flag[NPROD] = {};
__device__ int g_dflag[NBATCH] = {};

typedef float f32x4 __attribute__((ext_vector_type(4)));
typedef short bf16x8 __attribute__((ext_vector_type(8)));

__device__ __forceinline__ unsigned short f2b(float x) {
    unsigned u = __float_as_uint(x);
    u += 0x7FFFu + ((u >> 16) & 1u);
    return (unsigned short)(u >> 16);
}

__device__ __forceinline__ void st_agent(float* p, float v) {
    __hip_atomic_store(p, v, __ATOMIC_RELAXED, __HIP_MEMORY_SCOPE_AGENT);
}
__device__ __forceinline__ void st_flag(int* p, int v) {
    __hip_atomic_store(p, v, __ATOMIC_RELAXED, __HIP_MEMORY_SCOPE_AGENT);
}
__device__ __forceinline__ int ld_flag(const int* p) {
    return __hip_atomic_load(p, __ATOMIC_RELAXED, __HIP_MEMORY_SCOPE_AGENT);
}

__global__ __launch_bounds__(1024) void kOne(
        const float* __restrict__ pooled,
        const int*   __restrict__ spk,
        const float* __restrict__ emo_w,
        const float* __restrict__ emo_b,
        const float* __restrict__ gate_w,
        const float* __restrict__ gate_b,
        const float* __restrict__ w1,
        const float* __restrict__ b1,
        const float* __restrict__ w2,
        const float* __restrict__ b2,
        float* __restrict__ out,                // [1024*7] emo | [33280*2] cause
        float* __restrict__ wsBt) {             // [8][776] f32
    const int blk = blockIdx.x;
    const int tid = threadIdx.x;
    const int l   = tid & 63;
    const int wv  = tid >> 6;

    // ================= producer blocks: one M-row per wave =================
    if (blk < NPROD) {
        const int mr = blk * 16 + wv;                     // 0..3103
        const int e = mr / 1552, rr = mr - e * 1552;
        const float4 a = ((const float4*)(w1 + ((size_t)e * 1552 + rr) * 256))[l];
        const float4* wvp = (const float4*)(w2 + (size_t)e * 512);
        const float4 q0 = wvp[l * 2], q1 = wvp[l * 2 + 1];
        float a0 = a.x * q0.x + a.y * q0.z + a.z * q1.x + a.w * q1.z;
        float a1 = a.x * q0.y + a.y * q0.w + a.z * q1.y + a.w * q1.w;
#pragma unroll
        for (int off = 32; off; off >>= 1) {
            a0 += __shfl_down(a0, off);
            a1 += __shfl_down(a1, off);
        }
        if (l == 0) {
            const int half = rr / FEAT_, f = rr - half * FEAT_;
            const int j = half * 4 + e * 2;
            st_agent(wsBt + j * WKP + f, a0);
            st_agent(wsBt + (j + 1) * WKP + f, a1);
        }
        __syncthreads();                 // drains vmcnt: stores at coherence point
        if (tid == 0) st_flag(&g_flag[blk], 1);
        return;
    }

    // ================= consumer blocks (one per batch) =================
    const int b = blk - CONS0, R0 = b * 64;
    __shared__ __align__(16) short sBt[12 * LKP];         // 19,392 B
    __shared__ float emoL[64][8];                         //  2,048 B
    __shared__ float part[4096];                          // 16,384 B
    __shared__ float bcL[4];

    const int m = wv & 3, kq = wv >> 2, g = l >> 4, n = l & 15;
    const int arow = R0 + m * 16 + n;
    const int kt0 = (kq == 0) ? 0 : (1 + 6 * kq);         // k-steps 7,6,6,6
    const int cnt = (kq == 0) ? 7 : 6;

    // --- pre-work 1: A-fragment preload from pooled (producer-independent) ---
    bf16x8 af[7];
#pragma unroll
    for (int s = 0; s < 7; ++s) {
        bf16x8 t = {0, 0, 0, 0, 0, 0, 0, 0};
        if (s < cnt) {
            const int k0 = (kt0 + s) * 32 + g * 8;
            if (k0 < H_) {
                const float4 u0 = *(const float4*)(pooled + (size_t)arow * H_ + k0);
                const float4 u1 = *(const float4*)(pooled + (size_t)arow * H_ + k0 + 4);
                t[0] = (short)f2b(u0.x); t[1] = (short)f2b(u0.y);
                t[2] = (short)f2b(u0.z); t[3] = (short)f2b(u0.w);
                t[4] = (short)f2b(u1.x); t[5] = (short)f2b(u1.y);
                t[6] = (short)f2b(u1.z); t[7] = (short)f2b(u1.w);
            }
        }
        af[s] = t;
    }

    // --- pre-work 2: gate rows 8..11 of sBt straight from gate_w + pads ---
    for (int gi = tid; gi < 3104; gi += 1024) {
        const int half = gi >> 11 ? 1 : gi / 1552;        // gi/1552
        const int r2 = gi - half * 1552, f = r2 >> 1, c = r2 & 1;
        sBt[(8 + half * 2 + c) * LKP + f] =
            (short)f2b(gate_w[((size_t)half * FEAT_ + f) * 2 + c]);
    }
    for (int z = tid; z < 12 * 32; z += 1024) {           // zero pad f 776..807
        const int j = z >> 5, f = FEAT_ + (z & 31);
        sBt[j * LKP + f] = 0;
    }

    // --- pre-work 3: bias consts (redundant per block, waves 0/1) ---
    if (wv < 2) {
        const int e = wv;
        const float4 a = ((const float4*)(b1 + e * 256))[l];
        const float4* wvp = (const float4*)(w2 + (size_t)e * 512);
        const float4 q0 = wvp[l * 2], q1 = wvp[l * 2 + 1];
        float a0 = a.x * q0.x + a.y * q0.z + a.z * q1.x + a.w * q1.z;
        float a1 = a.x * q0.y + a.y * q0.w + a.z * q1.y + a.w * q1.w;
#pragma unroll
        for (int off = 32; off; off >>= 1) {
            a0 += __shfl_down(a0, off);
            a1 += __shfl_down(a1, off);
        }
        if (l == 0) {
            bcL[e * 2]     = a0 + b2[e * 2];
            bcL[e * 2 + 1] = a1 + b2[e * 2 + 1];
        }
    }

    // --- pre-work 4: emotion rows (wave wv -> 4 rows) ---
#pragma unroll
    for (int r4 = 0; r4 < 4; ++r4) {
        const int lr = wv * 4 + r4;
        const float* pr = pooled + (size_t)(R0 + lr) * H_;
        float acc[NE_] = {0.f, 0.f, 0.f, 0.f, 0.f, 0.f, 0.f};
#pragma unroll
        for (int i = 0; i < 12; ++i) {
            const float p = pr[l + 64 * i];
            const float* ew = emo_w + (size_t)(l + 64 * i) * NE_;
#pragma unroll
            for (int k = 0; k < NE_; ++k) acc[k] += p * ew[k];
        }
#pragma unroll
        for (int off = 32; off; off >>= 1)
#pragma unroll
            for (int k = 0; k < NE_; ++k) acc[k] += __shfl_down(acc[k], off);
        if (l == 0) {
#pragma unroll
            for (int k = 0; k < NE_; ++k) {
                const float v = acc[k] + emo_b[k];
                out[(size_t)(R0 + lr) * NE_ + k] = v;
                emoL[lr][k] = v;
            }
            emoL[lr][7] = (float)spk[R0 + lr];
        }
    }
    __syncthreads();

    // emotion/spk A-fragment fixup (k 768..775): kq==3, s=5 -> kt=24, g==0
    if (kq == 3 && g == 0) {
        const int lr = m * 16 + n;
        bf16x8 t;
        t[0] = (short)f2b(emoL[lr][0]); t[1] = (short)f2b(emoL[lr][1]);
        t[2] = (short)f2b(emoL[lr][2]); t[3] = (short)f2b(emoL[lr][3]);
        t[4] = (short)f2b(emoL[lr][4]); t[5] = (short)f2b(emoL[lr][5]);
        t[6] = (short)f2b(emoL[lr][6]); t[7] = (short)f2b(emoL[lr][7]);
        af[5] = t;
    }

    // --- handoff: per-lane flag polling (loads only, no RMW) ---
    if (tid < NPROD) {
        int guard = 0;
        while (ld_flag(&g_flag[tid]) == 0 && ++guard < (1 << 22))
            __builtin_amdgcn_s_sleep(1);
    }
    __syncthreads();

    // --- stage M rows 0..7 of Bt -> LDS bf16 (sc1 loads, coherent) ---
    for (int i = tid; i < 8 * (WKP / 2); i += 1024) {     // 3104 float2
        const int j = i / (WKP / 2), kk = (i - j * (WKP / 2)) * 2;
        const unsigned long long v = __hip_atomic_load(
            (const unsigned long long*)(wsBt + j * WKP + kk),
            __ATOMIC_RELAXED, __HIP_MEMORY_SCOPE_AGENT);
        sBt[j * LKP + kk]     = (short)f2b(__uint_as_float((unsigned)v));
        sBt[j * LKP + kk + 1] = (short)f2b(__uint_as_float((unsigned)(v >> 32)));
    }
    __syncthreads();

    // --- MFMA: 25 k-steps over 4 k-quarters, 4 m-tiles, N=16 (12 used) ---
    f32x4 acc = {0.f, 0.f, 0.f, 0.f};
#pragma unroll
    for (int s = 0; s < 7; ++s) {
        if (s < cnt) {
            const int k0 = (kt0 + s) * 32 + g * 8;
            bf16x8 bfr = {0, 0, 0, 0, 0, 0, 0, 0};
            if (n < 12)
                bfr = *(const bf16x8*)(sBt + n * LKP + k0);
            acc = __builtin_amdgcn_mfma_f32_16x16x32_bf16(af[s], bfr, acc, 0, 0, 0);
        }
    }
#pragma unroll
    for (int i = 0; i < 4; ++i)
        part[(kq * 64 + m * 16 + g * 4 + i) * 16 + n] = acc[i];
    __syncthreads();

    // cross-kq reduce into part[0]
    {
        const int r = tid >> 4, c = tid & 15;
        const float v = part[r * 16 + c] + part[(64 + r) * 16 + c] +
                        part[(128 + r) * 16 + c] + part[(192 + r) * 16 + c];
        part[r * 16 + c] = v;
    }
    __syncthreads();

    // --- pairs: O(1) each from part[0] (pc[64][16]) ---
    const float bc0 = bcL[0], bc1 = bcL[1], bc2 = bcL[2], bc3 = bcL[3];
    const float gb0 = gate_b[0], gb1 = gate_b[1];
    float* oc = out + (size_t)NROW * NE_ + (size_t)b * PAIRS * 2;
    for (int p = tid; p < PAIRS; p += 1024) {
        int end = (int)((sqrtf(8.0f * (float)p + 1.0f) - 1.0f) * 0.5f);
        while ((end + 1) * (end + 2) / 2 <= p) end++;
        while (end * (end + 1) / 2 > p) end--;
        const int tt = p - end * (end + 1) / 2;
        const float* pt = part + tt * 16;
        const float* pe = part + end * 16;
        const float g0 = pt[8] + pe[10] + gb0;
        const float g1 = pt[9] + pe[11] + gb1;
        oc[p * 2]     = (pt[0] + pe[4] + bc0) * g0 + (pt[2] + pe[6] + bc2) * g1;
        oc[p * 2 + 1] = (pt[1] + pe[5] + bc1) * g0 + (pt[3] + pe[7] + bc3) * g1;
    }

    // --- depart + flag reset (block 0 only; store/load, no RMW) ---
    __syncthreads();
    if (tid == 0) st_flag(&g_dflag[b], 1);
    if (b == 0) {
        if (tid < NBATCH) {
            int guard = 0;
            while (ld_flag(&g_dflag[tid]) == 0 && ++guard < (1 << 22))
                __builtin_amdgcn_s_sleep(1);
        }
        __syncthreads();
        if (tid < NPROD) st_flag(&g_flag[tid], 0);
        if (tid < NBATCH) st_flag(&g_dflag[tid], 0);
    }
}

// ---------------------------------------------------------------------------
extern "C" void kernel_launch(void* const* d_in, const int* in_sizes, int n_in,
                              void* d_out, int out_size, void* d_ws, size_t ws_size,
                              hipStream_t stream) {
    const float* pooled = (const float*)d_in[0];
    const int*   spk    = (const int*)d_in[1];
    const float* emo_w  = (const float*)d_in[2];
    const float* emo_b  = (const float*)d_in[3];
    const float* gate_w = (const float*)d_in[4];
    const float* gate_b = (const float*)d_in[5];
    const float* exp_w1 = (const float*)d_in[6];
    const float* exp_b1 = (const float*)d_in[7];
    const float* exp_w2 = (const float*)d_in[8];
    const float* exp_b2 = (const float*)d_in[9];

    float* out  = (float*)d_out;
    float* wsBt = (float*)d_ws;                          // 8*776*4 = 24,832 B

    hipLaunchKernelGGL(kOne, dim3(NBLKS), dim3(1024), 0, stream,
                       pooled, spk, emo_w, emo_b, gate_w, gate_b,
                       exp_w1, exp_b1, exp_w2, exp_b2, out, wsBt);
}

// Round 8
// 18.468 us; speedup vs baseline: 2.0559x; 2.0414x over previous
//
#include <hip/hip_runtime.h>

// GuidedMoEBasic: B=16, D=64, H=768, NE=7, FEAT=776, 2*FEAT=1552
// Pairs per batch P = D*(D+1)/2 = 2080, N = 16*2080 = 33280.
//
// Structure = round-1 (best measured: 19.1us), bodies micro-trimmed.
// Measured session model: dur ~= 14-15us fixed replay overhead + sum(bodies);
// in-kernel cross-block sync costs >=18us extra in every flavor tried
// (grid.sync / fences / RMW / flag-stores) -> kernel boundary is the cheapest
// global barrier. 3 kernels: kM (M=W1@W2), kRow (emotion + 12 projections,
// fully float4-vectorized), kPair (O(1) per pair).

#define H_     768
#define NE_    7
#define FEAT_  776
#define TWOF   1552
#define NROW   1024
#define PAIRS  2080
#define NPAIR  33280
#define EXH    256

// workspace float layout
#define M_OFF  0        // 2*1552*2 = 6208 floats  (M[e*1552+half*776+f][c])
#define BC_OFF 6208     // 4 floats                 (bconst[e][c])
#define PC_OFF 6212     // 1024*12 floats           (pc[row][j])

// ---------------------------------------------------------------------------
// Kernel 1: M[e][r][c] = sum_h W1[e][r][h] * W2[e][h][c]   (one wave per row)
//           bconst[e][c] = sum_h b1[e][h] * W2[e][h][c] + b2[e][c]
// ---------------------------------------------------------------------------
__global__ __launch_bounds__(256) void kM(const float* __restrict__ w1,
                                          const float* __restrict__ b1,
                                          const float* __restrict__ w2,
                                          const float* __restrict__ b2,
                                          float* __restrict__ M,
                                          float* __restrict__ bc) {
    const int lane = threadIdx.x & 63;
    const int wave = threadIdx.x >> 6;
    const int blk  = blockIdx.x;

    int e, r = 0;
    float4 a;
    if (blk < 776) {
        const int row = blk * 4 + wave;          // 0..3103
        e = row / TWOF;
        r = row - e * TWOF;
        a = ((const float4*)(w1 + ((size_t)e * TWOF + r) * EXH))[lane];
    } else {
        if (wave >= 2) return;                   // whole-wave uniform exit
        e = wave;
        a = ((const float4*)(b1 + e * EXH))[lane];
    }

    const float4* wv = (const float4*)(w2 + (size_t)e * EXH * 2);
    const float4 q0 = wv[lane * 2];
    const float4 q1 = wv[lane * 2 + 1];
    float a0 = a.x * q0.x + a.y * q0.z + a.z * q1.x + a.w * q1.z;
    float a1 = a.x * q0.y + a.y * q0.w + a.z * q1.y + a.w * q1.w;

#pragma unroll
    for (int off = 32; off; off >>= 1) {
        a0 += __shfl_down(a0, off);
        a1 += __shfl_down(a1, off);
    }
    if (lane == 0) {
        if (blk < 776) {
            M[((size_t)e * TWOF + r) * 2 + 0] = a0;
            M[((size_t)e * TWOF + r) * 2 + 1] = a1;
        } else {
            bc[e * 2 + 0] = a0 + b2[e * 2 + 0];
            bc[e * 2 + 1] = a1 + b2[e * 2 + 1];
        }
    }
}

// ---------------------------------------------------------------------------
// Kernel 2: one block per utterance row (1024 blocks), fully float4.
//   emotion_pred[row] -> d_out and conc[768..774]; spk -> conc[775]
//   pc[row][j] = conc[row] . Bt[j]   for 8 M-columns + 4 gate columns
// ---------------------------------------------------------------------------
__global__ __launch_bounds__(256) void kRow(const float* __restrict__ pooled,
                                            const int* __restrict__ spk,
                                            const float* __restrict__ emo_w,
                                            const float* __restrict__ emo_b,
                                            const float* __restrict__ gate_w,
                                            const float* __restrict__ M,
                                            float* __restrict__ out_emo,
                                            float* __restrict__ pc) {
    __shared__ __align__(16) float conc[FEAT_];
    __shared__ float redE[4][NE_];
    __shared__ float redP[4][12];

    const int row  = blockIdx.x;
    const int t    = threadIdx.x;
    const int lane = t & 63;
    const int wave = t >> 6;

    // --- emotion head + stage pooled into LDS (float4: thread t -> f=4t..4t+3)
    float acc[NE_] = {0.f, 0.f, 0.f, 0.f, 0.f, 0.f, 0.f};
    if (t < 192) {
        const float4 c4 = *(const float4*)(pooled + (size_t)row * H_ + 4 * t);
        *(float4*)(conc + 4 * t) = c4;
        const float* ew = emo_w + (size_t)(4 * t) * NE_;
#pragma unroll
        for (int k = 0; k < NE_; k++)
            acc[k] = c4.x * ew[k] + c4.y * ew[NE_ + k] +
                     c4.z * ew[2 * NE_ + k] + c4.w * ew[3 * NE_ + k];
    }
#pragma unroll
    for (int off = 32; off; off >>= 1)
#pragma unroll
        for (int k = 0; k < NE_; k++) acc[k] += __shfl_down(acc[k], off);
    if (lane == 0)
#pragma unroll
        for (int k = 0; k < NE_; k++) redE[wave][k] = acc[k];
    __syncthreads();

    if (t < NE_) {
        const float v = emo_b[t] + redE[0][t] + redE[1][t] + redE[2][t] + redE[3][t];
        out_emo[row * NE_ + t] = v;
        conc[H_ + t] = v;
    } else if (t == NE_) {
        conc[FEAT_ - 1] = (float)spk[row];
    }
    __syncthreads();

    // --- 12 projections, all float4 (thread t -> f=4t..4t+3, t<194)
    float pa[12] = {0.f, 0.f, 0.f, 0.f, 0.f, 0.f, 0.f, 0.f, 0.f, 0.f, 0.f, 0.f};
    if (t < 194) {
        const float4 c4 = *(const float4*)(conc + 4 * t);
#pragma unroll
        for (int half = 0; half < 2; ++half) {
#pragma unroll
            for (int e = 0; e < 2; ++e) {
                const float* mb = M + ((size_t)e * TWOF + half * FEAT_ + 4 * t) * 2;
                const float4 v0 = *(const float4*)mb;
                const float4 v1 = *(const float4*)(mb + 4);
                const int j = half * 4 + e * 2;
                pa[j]     += c4.x * v0.x + c4.y * v0.z + c4.z * v1.x + c4.w * v1.z;
                pa[j + 1] += c4.x * v0.y + c4.y * v0.w + c4.z * v1.y + c4.w * v1.w;
            }
            const float* gb = gate_w + ((size_t)half * FEAT_ + 4 * t) * 2;
            const float4 g0 = *(const float4*)gb;
            const float4 g1 = *(const float4*)(gb + 4);
            pa[8 + half * 2]     += c4.x * g0.x + c4.y * g0.z + c4.z * g1.x + c4.w * g1.z;
            pa[8 + half * 2 + 1] += c4.x * g0.y + c4.y * g0.w + c4.z * g1.y + c4.w * g1.w;
        }
    }
#pragma unroll
    for (int off = 32; off; off >>= 1)
#pragma unroll
        for (int k = 0; k < 12; k++) pa[k] += __shfl_down(pa[k], off);
    if (lane == 0)
#pragma unroll
        for (int k = 0; k < 12; k++) redP[wave][k] = pa[k];
    __syncthreads();

    if (t < 12)
        pc[row * 12 + t] = redP[0][t] + redP[1][t] + redP[2][t] + redP[3][t];
}

// ---------------------------------------------------------------------------
// Kernel 3: one thread per pair. O(1) work per pair from pc vectors.
// ---------------------------------------------------------------------------
__global__ __launch_bounds__(256) void kPair(const float* __restrict__ pc,
                                             const float* __restrict__ bc,
                                             const float* __restrict__ gate_b,
                                             float* __restrict__ out_cause) {
    const int n = blockIdx.x * 256 + threadIdx.x;
    if (n >= NPAIR) return;
    const int b = n / PAIRS;
    const int p = n - b * PAIRS;

    int end = (int)((sqrtf(8.0f * (float)p + 1.0f) - 1.0f) * 0.5f);
    while ((end + 1) * (end + 2) / 2 <= p) end++;
    while (end * (end + 1) / 2 > p) end--;
    const int tt = p - end * (end + 1) / 2;

    const float* pt = pc + ((size_t)b * 64 + tt) * 12;   // first-half (t) row
    const float* pe = pc + ((size_t)b * 64 + end) * 12;  // second-half (end) row

    const float g0 = pt[8] + pe[10] + gate_b[0];
    const float g1 = pt[9] + pe[11] + gate_b[1];

    const float o00 = pt[0] + pe[4] + bc[0];
    const float o01 = pt[1] + pe[5] + bc[1];
    const float o10 = pt[2] + pe[6] + bc[2];
    const float o11 = pt[3] + pe[7] + bc[3];

    out_cause[(size_t)n * 2 + 0] = o00 * g0 + o10 * g1;
    out_cause[(size_t)n * 2 + 1] = o01 * g0 + o11 * g1;
}

// ---------------------------------------------------------------------------
extern "C" void kernel_launch(void* const* d_in, const int* in_sizes, int n_in,
                              void* d_out, int out_size, void* d_ws, size_t ws_size,
                              hipStream_t stream) {
    const float* pooled = (const float*)d_in[0];
    const int*   spk    = (const int*)d_in[1];
    const float* emo_w  = (const float*)d_in[2];
    const float* emo_b  = (const float*)d_in[3];
    const float* gate_w = (const float*)d_in[4];
    const float* gate_b = (const float*)d_in[5];
    const float* exp_w1 = (const float*)d_in[6];
    const float* exp_b1 = (const float*)d_in[7];
    const float* exp_w2 = (const float*)d_in[8];
    const float* exp_b2 = (const float*)d_in[9];

    float* out = (float*)d_out;                 // [1024*7] emotion | [33280*2] cause
    float* W   = (float*)d_ws;
    float* M   = W + M_OFF;
    float* bc  = W + BC_OFF;
    float* pc  = W + PC_OFF;

    hipLaunchKernelGGL(kM, dim3(777), dim3(256), 0, stream,
                       exp_w1, exp_b1, exp_w2, exp_b2, M, bc);
    hipLaunchKernelGGL(kRow, dim3(NROW), dim3(256), 0, stream,
                       pooled, spk, emo_w, emo_b, gate_w, M, out, pc);
    hipLaunchKernelGGL(kPair, dim3((NPAIR + 255) / 256), dim3(256), 0, stream,
                       pc, bc, gate_b, out + NROW * NE_);
}

// Round 9
// 17.409 us; speedup vs baseline: 2.1810x; 1.0608x over previous
//
#include <hip/hip_runtime.h>

// GuidedMoEBasic: B=16, D=64, H=768, NE=7, FEAT=776, 2*FEAT=1552
// P = D*(D+1)/2 = 2080 pairs/batch, N = 16*2080 = 33280.
//
// Affine collapse: expert MLP has no nonlinearity ->
//   o[e,n,:] = flat[n]@(W1[e]@W2[e]) + (b1[e]@W2[e]+b2[e]),
//   flat[n] = [conc[b,t], conc[b,end]] -> per-row 12-float pc vectors,
//   cause per pair is O(1) from pc.
// Session model (R1..R8): dur ~= 14-15us fixed replay overhead + sum(bodies);
// all in-kernel cross-block sync flavors measured >= +18us vs kernel
// boundaries. 3 kernels, bodies minimized:
//   kPre : M=W1@W2 + bias consts (blocks 0..776) || emotion rows (777..1032)
//   kProj: 12 projections/row, conc never staged (per-thread c4 registers)
//   kPair: O(1) per pair, float4 pc reads (stride padded to 16)

#define H_     768
#define NE_    7
#define FEAT_  776
#define TWOF   1552
#define NROW   1024
#define PAIRS  2080
#define NPAIR  33280
#define EXH    256

// workspace float layout
#define M_OFF   0          // 6208 floats: M[(e*1552 + half*776 + f)*2 + c]
#define BC_OFF  6208       // 4 floats
#define EMO_OFF 6212       // 1024*8: [row][0..6]=emotion, [7]=spk (float)
#define PC_OFF  14404      // 1024*16: pc[row][j], j<12 used (16B-aligned)

// ---------------------------------------------------------------------------
// K1: blocks 0..775 -> M rows (1 per wave); 776 -> bias consts;
//     777..1032 -> emotion (1 row per wave, 4 rows/block).
// ---------------------------------------------------------------------------
__global__ __launch_bounds__(256) void kPre(const float* __restrict__ w1,
                                            const float* __restrict__ b1,
                                            const float* __restrict__ w2,
                                            const float* __restrict__ b2,
                                            const float* __restrict__ pooled,
                                            const int* __restrict__ spk,
                                            const float* __restrict__ emo_w,
                                            const float* __restrict__ emo_b,
                                            float* __restrict__ W,
                                            float* __restrict__ out_emo) {
    const int lane = threadIdx.x & 63;
    const int wave = threadIdx.x >> 6;
    const int blk  = blockIdx.x;

    if (blk < 777) {
        // ---- M / bias: one 256-deep dot pair per wave ----
        int e, r = 0;
        float4 a;
        if (blk < 776) {
            const int row = blk * 4 + wave;          // 0..3103
            e = row / TWOF;
            r = row - e * TWOF;
            a = ((const float4*)(w1 + ((size_t)e * TWOF + r) * EXH))[lane];
        } else {
            if (wave >= 2) return;                   // whole-wave uniform exit
            e = wave;
            a = ((const float4*)(b1 + e * EXH))[lane];
        }
        const float4* wv = (const float4*)(w2 + (size_t)e * EXH * 2);
        const float4 q0 = wv[lane * 2];
        const float4 q1 = wv[lane * 2 + 1];
        float a0 = a.x * q0.x + a.y * q0.z + a.z * q1.x + a.w * q1.z;
        float a1 = a.x * q0.y + a.y * q0.w + a.z * q1.y + a.w * q1.w;
#pragma unroll
        for (int off = 32; off; off >>= 1) {
            a0 += __shfl_down(a0, off);
            a1 += __shfl_down(a1, off);
        }
        if (lane == 0) {
            if (blk < 776) {
                W[M_OFF + ((size_t)e * TWOF + r) * 2 + 0] = a0;
                W[M_OFF + ((size_t)e * TWOF + r) * 2 + 1] = a1;
            } else {
                W[BC_OFF + e * 2 + 0] = a0 + b2[e * 2 + 0];
                W[BC_OFF + e * 2 + 1] = a1 + b2[e * 2 + 1];
            }
        }
        return;
    }

    // ---- emotion: one row per wave ----
    const int row = (blk - 777) * 4 + wave;          // 0..1023
    const float* pr = pooled + (size_t)row * H_;
    float acc[NE_] = {0.f, 0.f, 0.f, 0.f, 0.f, 0.f, 0.f};
#pragma unroll
    for (int i = 0; i < 12; ++i) {
        const float p = pr[lane + 64 * i];
        const float* ew = emo_w + (size_t)(lane + 64 * i) * NE_;
#pragma unroll
        for (int k = 0; k < NE_; ++k) acc[k] += p * ew[k];
    }
#pragma unroll
    for (int off = 32; off; off >>= 1)
#pragma unroll
        for (int k = 0; k < NE_; ++k) acc[k] += __shfl_down(acc[k], off);
    if (lane == 0) {
        float* er = W + EMO_OFF + (size_t)row * 8;
#pragma unroll
        for (int k = 0; k < NE_; ++k) {
            const float v = acc[k] + emo_b[k];
            out_emo[(size_t)row * NE_ + k] = v;
            er[k] = v;
        }
        er[7] = (float)spk[row];
    }
}

// ---------------------------------------------------------------------------
// K2: one block per row. Thread t owns features 4t..4t+3 (t<194); c4 straight
// from pooled / ws-emo registers -> 12 projections -> shfl + LDS reduce.
// ---------------------------------------------------------------------------
__global__ __launch_bounds__(256) void kProj(const float* __restrict__ pooled,
                                             const float* __restrict__ gate_w,
                                             const float* __restrict__ W,
                                             float* __restrict__ pc) {
    __shared__ float redP[4][12];

    const int row  = blockIdx.x;
    const int t    = threadIdx.x;
    const int lane = t & 63;
    const int wave = t >> 6;

    float4 c4 = {0.f, 0.f, 0.f, 0.f};
    if (t < 192) {
        c4 = *(const float4*)(pooled + (size_t)row * H_ + 4 * t);
    } else if (t < 194) {
        c4 = *(const float4*)(W + EMO_OFF + (size_t)row * 8 + (t - 192) * 4);
    }

    float pa[12] = {0.f, 0.f, 0.f, 0.f, 0.f, 0.f, 0.f, 0.f, 0.f, 0.f, 0.f, 0.f};
    if (t < 194) {
        const float* M = W + M_OFF;
#pragma unroll
        for (int half = 0; half < 2; ++half) {
#pragma unroll
            for (int e = 0; e < 2; ++e) {
                const float* mb = M + ((size_t)e * TWOF + half * FEAT_ + 4 * t) * 2;
                const float4 v0 = *(const float4*)mb;
                const float4 v1 = *(const float4*)(mb + 4);
                const int j = half * 4 + e * 2;
                pa[j]     += c4.x * v0.x + c4.y * v0.z + c4.z * v1.x + c4.w * v1.z;
                pa[j + 1] += c4.x * v0.y + c4.y * v0.w + c4.z * v1.y + c4.w * v1.w;
            }
            const float* gb = gate_w + ((size_t)half * FEAT_ + 4 * t) * 2;
            const float4 g0 = *(const float4*)gb;
            const float4 g1 = *(const float4*)(gb + 4);
            pa[8 + half * 2]     += c4.x * g0.x + c4.y * g0.z + c4.z * g1.x + c4.w * g1.z;
            pa[8 + half * 2 + 1] += c4.x * g0.y + c4.y * g0.w + c4.z * g1.y + c4.w * g1.w;
        }
    }
#pragma unroll
    for (int off = 32; off; off >>= 1)
#pragma unroll
        for (int k = 0; k < 12; ++k) pa[k] += __shfl_down(pa[k], off);
    if (lane == 0)
#pragma unroll
        for (int k = 0; k < 12; ++k) redP[wave][k] = pa[k];
    __syncthreads();

    if (t < 12)
        pc[(size_t)row * 16 + t] = redP[0][t] + redP[1][t] + redP[2][t] + redP[3][t];
}

// ---------------------------------------------------------------------------
// K3: one thread per pair; float4 pc reads (stride 16).
// ---------------------------------------------------------------------------
__global__ __launch_bounds__(256) void kPair(const float* __restrict__ pc,
                                             const float* __restrict__ bc,
                                             const float* __restrict__ gate_b,
                                             float* __restrict__ out_cause) {
    const int n = blockIdx.x * 256 + threadIdx.x;
    if (n >= NPAIR) return;
    const int b = n / PAIRS;
    const int p = n - b * PAIRS;

    int end = (int)((sqrtf(8.0f * (float)p + 1.0f) - 1.0f) * 0.5f);
    while ((end + 1) * (end + 2) / 2 <= p) end++;
    while (end * (end + 1) / 2 > p) end--;
    const int tt = p - end * (end + 1) / 2;

    const float* pt = pc + ((size_t)b * 64 + tt) * 16;
    const float* pe = pc + ((size_t)b * 64 + end) * 16;
    const float4 u0 = *(const float4*)pt;          // pt[0..3]
    const float4 u2 = *(const float4*)(pt + 8);    // pt[8..11]
    const float4 v1 = *(const float4*)(pe + 4);    // pe[4..7]
    const float4 v2 = *(const float4*)(pe + 8);    // pe[8..11]

    const float g0 = u2.x + v2.z + gate_b[0];
    const float g1 = u2.y + v2.w + gate_b[1];

    const float o00 = u0.x + v1.x + bc[0];
    const float o01 = u0.y + v1.y + bc[1];
    const float o10 = u0.z + v1.z + bc[2];
    const float o11 = u0.w + v1.w + bc[3];

    out_cause[(size_t)n * 2 + 0] = o00 * g0 + o10 * g1;
    out_cause[(size_t)n * 2 + 1] = o01 * g0 + o11 * g1;
}

// ---------------------------------------------------------------------------
extern "C" void kernel_launch(void* const* d_in, const int* in_sizes, int n_in,
                              void* d_out, int out_size, void* d_ws, size_t ws_size,
                              hipStream_t stream) {
    const float* pooled = (const float*)d_in[0];
    const int*   spk    = (const int*)d_in[1];
    const float* emo_w  = (const float*)d_in[2];
    const float* emo_b  = (const float*)d_in[3];
    const float* gate_w = (const float*)d_in[4];
    const float* gate_b = (const float*)d_in[5];
    const float* exp_w1 = (const float*)d_in[6];
    const float* exp_b1 = (const float*)d_in[7];
    const float* exp_w2 = (const float*)d_in[8];
    const float* exp_b2 = (const float*)d_in[9];

    float* out = (float*)d_out;                 // [1024*7] emotion | [33280*2] cause
    float* W   = (float*)d_ws;

    hipLaunchKernelGGL(kPre, dim3(1033), dim3(256), 0, stream,
                       exp_w1, exp_b1, exp_w2, exp_b2,
                       pooled, spk, emo_w, emo_b, W, out);
    hipLaunchKernelGGL(kProj, dim3(NROW), dim3(256), 0, stream,
                       pooled, gate_w, W, W + PC_OFF);
    hipLaunchKernelGGL(kPair, dim3((NPAIR + 255) / 256), dim3(256), 0, stream,
                       W + PC_OFF, W + BC_OFF, gate_b, out + NROW * NE_);
}